// Round 7
// baseline (216.536 us; speedup 1.0000x reference)
//
#include <hip/hip_runtime.h>

namespace {
constexpr int NB = 32;      // batch
constexpr int NN = 2000;    // nodes
constexpr int NE = 64000;   // edges
constexpr int ND = 128;     // feature dim
constexpr int TR = 32;      // tile rows
constexpr int NCHUNK = (NN + TR - 1) / TR;   // 63
constexpr int NXCD = 8;
constexpr int BPB = 2;                        // batches per block
constexpr int PAIRS = NB / (NXCD * BPB);      // batch-pairs per XCD = 2
constexpr int GRID_FUSED = NXCD * PAIRS * NCHUNK;  // 1008
constexpr int SL = 80;      // slot stride per node (max in-deg ~52 expected; huge margin)
constexpr int ECAP = 1536;  // dense staged-edge cap per tile (mean 1024, sd ~32)

// ---- workspace layout (bytes) ----
constexpr size_t OFF_CNT  = 0;                          // int[2048]    (memset 0)
constexpr size_t OFF_WSUM = OFF_CNT + 2048 * 4;         // float[2048]  (memset 0)
constexpr size_t OFF_SLOT = OFF_WSUM + 2048 * 4;        // int[NN*SL]
constexpr size_t OFF_YP   = OFF_SLOT + (size_t)NN * SL * 4;  // float[NB*NCHUNK*ND]
constexpr size_t MEMSET_BYTES = 2048 * 4 * 2;           // cnt + wsum
} // namespace

// ---- S1: histogram + slot fill in one edge-parallel pass ----
__global__ void k_fill(const int* __restrict__ src, const int* __restrict__ dst,
                       int* __restrict__ cnt, int* __restrict__ slot) {
    int e = blockIdx.x * 256 + threadIdx.x;
    if (e < NE) {
        int s = src[e], d = dst[e];
        int p = atomicAdd(&cnt[d], 1);
        if (p < SL) slot[d * SL + p] = s;    // overflow essentially impossible
    }
}

// ---- S2: wsum out-edge terms (needs final cnt) ----
__global__ void k_wsum(const int* __restrict__ src, const int* __restrict__ dst,
                       const int* __restrict__ cnt, float* __restrict__ wsum) {
    int e = blockIdx.x * 256 + threadIdx.x;
    if (e < NE) {
        int s = src[e], d = dst[e];
        float w = rsqrtf((float)(cnt[s] + 1)) * rsqrtf((float)(cnt[d] + 1));
        atomicAdd(&wsum[s], w);
    }
}

// ---- fused: stage edges once, gather 2 batches, GEMM 2 batches, reduce ----
__global__ __launch_bounds__(256, 3) void k_fused(const float* __restrict__ X,
                                                  const int* __restrict__ cnt,
                                                  const int* __restrict__ slot,
                                                  const float* __restrict__ wsum,
                                                  const float* __restrict__ W1,
                                                  const float* __restrict__ b1,
                                                  float* __restrict__ ypart) {
    __shared__ float4 As4[2][32 * 33];   // 33792 B, row stride 33 float4
    __shared__ int2   sEdge[ECAP];       // 12288 B (src, w-bits), dense per tile
    __shared__ int    sCnt[32];
    __shared__ int    sBase[33];
    __shared__ float  sDinv[32];
    __shared__ float  yred[2][128];
    const int tid = threadIdx.x;

    // XCD batch-partition swizzle; block handles batches b0, b0+1 (same graph)
    const int L     = blockIdx.x;
    const int xcd   = L & (NXCD - 1);
    const int sl    = L >> 3;
    const int pair  = sl / NCHUNK;            // 0..PAIRS-1
    const int chunk = sl % NCHUNK;
    const int b0    = xcd * (BPB * PAIRS) + pair * BPB;
    const int n0    = chunk * TR;

    // per-row metadata
    if (tid < 32) {
        int n = n0 + tid;
        int cr = (n < NN) ? cnt[n] : 0;
        sCnt[tid]  = min(cr, SL);
        sDinv[tid] = rsqrtf((float)(cr + 1));
    }
    if (tid < 128) { yred[0][tid] = 0.f; yred[1][tid] = 0.f; }
    __syncthreads();
    if (tid == 0) {
        int s = 0;
        for (int j = 0; j < 32; j++) { sBase[j] = s; s += sCnt[j]; }
        sBase[32] = s;
    }
    __syncthreads();
    const bool staged = (sBase[32] <= ECAP);

    // stage edges: wave wv stages rows wv*8..+7; compute w at staging time
    const int wv = tid >> 6, ln = tid & 63;
    if (staged) {
        for (int ii = 0; ii < 8; ii++) {
            int j = wv * 8 + ii;
            int c = sCnt[j];
            float dd = sDinv[j];
            const int* sp = &slot[(size_t)(n0 + j) * SL];
            for (int base = 0; base < c; base += 64) {
                if (base + ln < c) {
                    int sidx = sp[base + ln];
                    float w = rsqrtf((float)(cnt[sidx] + 1)) * dd;
                    sEdge[sBase[j] + base + ln] = make_int2(sidx, __float_as_int(w));
                }
            }
        }
    }
    __syncthreads();

    // ---- gather: wave owns row; lane owns float2 slot; 16 loads in flight ----
    const float2* __restrict__ Xb0 = (const float2*)(X + (size_t)b0 * NN * ND);
    const float2* __restrict__ Xb1 = (const float2*)(X + (size_t)(b0 + 1) * NN * ND);
    float2* A0 = (float2*)As4[0];   // row stride 66 float2
    float2* A1 = (float2*)As4[1];
    #pragma unroll 1
    for (int ii = 0; ii < 8; ii++) {
        const int j = wv * 8 + ii;
        const int n = n0 + j;
        float2 a0 = make_float2(0.f, 0.f), a1 = a0, a0b = a0, a1b = a0;
        if (n < NN) {
            float sn = sDinv[j]; sn *= sn;
            float2 x0 = Xb0[n * 64 + ln], x1 = Xb1[n * 64 + ln];
            a0.x = sn * x0.x; a0.y = sn * x0.y;
            a1.x = sn * x1.x; a1.y = sn * x1.y;
            const int c = sCnt[j];
            if (staged) {
                const int e0 = sBase[j], e1 = e0 + c;
                int e = e0;
                for (; e + 8 <= e1; e += 8) {
                    int sidx[8]; float w[8]; float2 xs0[8], xs1[8];
                    #pragma unroll
                    for (int q = 0; q < 8; q++) {
                        int2 ed = sEdge[e + q];
                        sidx[q] = ed.x; w[q] = __int_as_float(ed.y);
                    }
                    #pragma unroll
                    for (int q = 0; q < 8; q++) {      // 16 independent 512B loads
                        xs0[q] = Xb0[sidx[q] * 64 + ln];
                        xs1[q] = Xb1[sidx[q] * 64 + ln];
                    }
                    #pragma unroll
                    for (int q = 0; q < 8; q++) {      // dual accumulators: short chains
                        if (q & 1) {
                            a0b.x = fmaf(w[q], xs0[q].x, a0b.x);
                            a0b.y = fmaf(w[q], xs0[q].y, a0b.y);
                            a1b.x = fmaf(w[q], xs1[q].x, a1b.x);
                            a1b.y = fmaf(w[q], xs1[q].y, a1b.y);
                        } else {
                            a0.x = fmaf(w[q], xs0[q].x, a0.x);
                            a0.y = fmaf(w[q], xs0[q].y, a0.y);
                            a1.x = fmaf(w[q], xs1[q].x, a1.x);
                            a1.y = fmaf(w[q], xs1[q].y, a1.y);
                        }
                    }
                }
                for (; e < e1; e++) {
                    int2 ed = sEdge[e];
                    float w = __int_as_float(ed.y);
                    float2 xs0 = Xb0[ed.x * 64 + ln], xs1 = Xb1[ed.x * 64 + ln];
                    a0.x = fmaf(w, xs0.x, a0.x); a0.y = fmaf(w, xs0.y, a0.y);
                    a1.x = fmaf(w, xs1.x, a1.x); a1.y = fmaf(w, xs1.y, a1.y);
                }
            } else {
                // astronomically-rare fallback: read slots directly
                const int* sp = &slot[(size_t)n * SL];
                float dd = sDinv[j];
                for (int e = 0; e < c; e++) {
                    int sidx = sp[e];
                    float w = rsqrtf((float)(cnt[sidx] + 1)) * dd;
                    float2 xs0 = Xb0[sidx * 64 + ln], xs1 = Xb1[sidx * 64 + ln];
                    a0.x = fmaf(w, xs0.x, a0.x); a0.y = fmaf(w, xs0.y, a0.y);
                    a1.x = fmaf(w, xs1.x, a1.x); a1.y = fmaf(w, xs1.y, a1.y);
                }
            }
            a0.x += a0b.x; a0.y += a0b.y;
            a1.x += a1b.x; a1.y += a1b.y;
        }
        A0[j * 66 + ln] = a0;
        A1[j * 66 + ln] = a1;
    }
    __syncthreads();

    // ---- GEMM both batches, sharing W loads ----
    const int c4 = tid & 31, rg = tid >> 5;
    float4 acc0[4], acc1[4];
    #pragma unroll
    for (int i = 0; i < 4; i++) {
        acc0[i] = make_float4(0.f, 0.f, 0.f, 0.f);
        acc1[i] = make_float4(0.f, 0.f, 0.f, 0.f);
    }
    const float4* __restrict__ W4 = (const float4*)W1 + c4;
    #pragma unroll 2
    for (int k4 = 0; k4 < 32; k4++) {
        float4 w0 = W4[(4 * k4 + 0) * 32];
        float4 w1 = W4[(4 * k4 + 1) * 32];
        float4 w2 = W4[(4 * k4 + 2) * 32];
        float4 w3 = W4[(4 * k4 + 3) * 32];
        #pragma unroll
        for (int i = 0; i < 4; i++) {
            float4 a = As4[0][(rg * 4 + i) * 33 + k4];
            acc0[i].x = fmaf(a.x, w0.x, acc0[i].x); acc0[i].x = fmaf(a.y, w1.x, acc0[i].x);
            acc0[i].x = fmaf(a.z, w2.x, acc0[i].x); acc0[i].x = fmaf(a.w, w3.x, acc0[i].x);
            acc0[i].y = fmaf(a.x, w0.y, acc0[i].y); acc0[i].y = fmaf(a.y, w1.y, acc0[i].y);
            acc0[i].y = fmaf(a.z, w2.y, acc0[i].y); acc0[i].y = fmaf(a.w, w3.y, acc0[i].y);
            acc0[i].z = fmaf(a.x, w0.z, acc0[i].z); acc0[i].z = fmaf(a.y, w1.z, acc0[i].z);
            acc0[i].z = fmaf(a.z, w2.z, acc0[i].z); acc0[i].z = fmaf(a.w, w3.z, acc0[i].z);
            acc0[i].w = fmaf(a.x, w0.w, acc0[i].w); acc0[i].w = fmaf(a.y, w1.w, acc0[i].w);
            acc0[i].w = fmaf(a.z, w2.w, acc0[i].w); acc0[i].w = fmaf(a.w, w3.w, acc0[i].w);
            float4 b = As4[1][(rg * 4 + i) * 33 + k4];
            acc1[i].x = fmaf(b.x, w0.x, acc1[i].x); acc1[i].x = fmaf(b.y, w1.x, acc1[i].x);
            acc1[i].x = fmaf(b.z, w2.x, acc1[i].x); acc1[i].x = fmaf(b.w, w3.x, acc1[i].x);
            acc1[i].y = fmaf(b.x, w0.y, acc1[i].y); acc1[i].y = fmaf(b.y, w1.y, acc1[i].y);
            acc1[i].y = fmaf(b.z, w2.y, acc1[i].y); acc1[i].y = fmaf(b.w, w3.y, acc1[i].y);
            acc1[i].z = fmaf(b.x, w0.z, acc1[i].z); acc1[i].z = fmaf(b.y, w1.z, acc1[i].z);
            acc1[i].z = fmaf(b.z, w2.z, acc1[i].z); acc1[i].z = fmaf(b.w, w3.z, acc1[i].z);
            acc1[i].w = fmaf(b.x, w0.w, acc1[i].w); acc1[i].w = fmaf(b.y, w1.w, acc1[i].w);
            acc1[i].w = fmaf(b.z, w2.w, acc1[i].w); acc1[i].w = fmaf(b.w, w3.w, acc1[i].w);
        }
    }

    // ---- epilogue: relu + weighted reduce, both batches ----
    float wn[4];
    #pragma unroll
    for (int i = 0; i < 4; i++) {
        int j = rg * 4 + i, n = n0 + j;
        float sd = sDinv[j];
        wn[i] = (n < NN) ? (wsum[n] + sd * sd) : 0.f;
    }
    float4 bias = ((const float4*)b1)[c4];
    float4 ya0 = make_float4(0.f, 0.f, 0.f, 0.f);
    float4 ya1 = ya0;
    #pragma unroll
    for (int i = 0; i < 4; i++) {
        ya0.x = fmaf(wn[i], fmaxf(acc0[i].x + bias.x, 0.f), ya0.x);
        ya0.y = fmaf(wn[i], fmaxf(acc0[i].y + bias.y, 0.f), ya0.y);
        ya0.z = fmaf(wn[i], fmaxf(acc0[i].z + bias.z, 0.f), ya0.z);
        ya0.w = fmaf(wn[i], fmaxf(acc0[i].w + bias.w, 0.f), ya0.w);
        ya1.x = fmaf(wn[i], fmaxf(acc1[i].x + bias.x, 0.f), ya1.x);
        ya1.y = fmaf(wn[i], fmaxf(acc1[i].y + bias.y, 0.f), ya1.y);
        ya1.z = fmaf(wn[i], fmaxf(acc1[i].z + bias.z, 0.f), ya1.z);
        ya1.w = fmaf(wn[i], fmaxf(acc1[i].w + bias.w, 0.f), ya1.w);
    }
    atomicAdd(&yred[0][4 * c4 + 0], ya0.x); atomicAdd(&yred[0][4 * c4 + 1], ya0.y);
    atomicAdd(&yred[0][4 * c4 + 2], ya0.z); atomicAdd(&yred[0][4 * c4 + 3], ya0.w);
    atomicAdd(&yred[1][4 * c4 + 0], ya1.x); atomicAdd(&yred[1][4 * c4 + 1], ya1.y);
    atomicAdd(&yred[1][4 * c4 + 2], ya1.z); atomicAdd(&yred[1][4 * c4 + 3], ya1.w);
    __syncthreads();
    if (tid < 128)
        ypart[((size_t)b0 * NCHUNK + chunk) * ND + tid] = yred[0][tid];
    else
        ypart[((size_t)(b0 + 1) * NCHUNK + chunk) * ND + (tid - 128)] = yred[1][tid - 128];
}

// ---- out[b,:] = (1/N) * (sum_chunk ypart[b,chunk,:]) @ W2 + b2 ----
__global__ __launch_bounds__(128) void k_out(const float* __restrict__ ypart,
                                             const float* __restrict__ W2,
                                             const float* __restrict__ b2,
                                             float* __restrict__ out) {
    __shared__ float ys[128];
    const int b = blockIdx.x;
    const int d = threadIdx.x;
    float s = 0.f;
    for (int c = 0; c < NCHUNK; c++)
        s += ypart[((size_t)b * NCHUNK + c) * ND + d];
    ys[d] = s * (1.f / (float)NN);
    __syncthreads();
    float acc = b2[d];
    #pragma unroll 8
    for (int k = 0; k < 128; k++)
        acc = fmaf(ys[k], W2[k * ND + d], acc);
    out[b * ND + d] = acc;
}

extern "C" void kernel_launch(void* const* d_in, const int* in_sizes, int n_in,
                              void* d_out, int out_size, void* d_ws, size_t ws_size,
                              hipStream_t stream) {
    (void)in_sizes; (void)n_in; (void)out_size; (void)ws_size;
    const float* X   = (const float*)d_in[0];
    const int*   src = (const int*)d_in[1];
    const int*   dst = (const int*)d_in[2];
    const float* W1  = (const float*)d_in[3];
    const float* b1  = (const float*)d_in[4];
    const float* W2  = (const float*)d_in[5];
    const float* b2  = (const float*)d_in[6];
    float* out = (float*)d_out;

    char* ws = (char*)d_ws;
    int*   cnt   = (int*)  (ws + OFF_CNT);
    float* wsum  = (float*)(ws + OFF_WSUM);
    int*   slot  = (int*)  (ws + OFF_SLOT);
    float* ypart = (float*)(ws + OFF_YP);

    hipMemsetAsync(ws, 0, MEMSET_BYTES, stream);                  // cnt + wsum
    k_fill<<<(NE + 255) / 256, 256, 0, stream>>>(src, dst, cnt, slot);
    k_wsum<<<(NE + 255) / 256, 256, 0, stream>>>(src, dst, cnt, wsum);
    k_fused<<<GRID_FUSED, 256, 0, stream>>>(X, cnt, slot, wsum, W1, b1, ypart);
    k_out<<<NB, 128, 0, stream>>>(ypart, W2, b2, out);
}

// Round 9
// 195.830 us; speedup vs baseline: 1.1057x; 1.1057x over previous
//
#include <hip/hip_runtime.h>

namespace {
constexpr int NB = 32;      // batch
constexpr int NN = 2000;    // nodes
constexpr int NE = 64000;   // edges
constexpr int ND = 128;     // feature dim
constexpr int TR = 32;      // tile rows
constexpr int NCHUNK = (NN + TR - 1) / TR;   // 63
constexpr int NXCD = 8;
constexpr int BPB = 2;                        // batches per block
constexpr int PAIRS = NB / (NXCD * BPB);      // batch-pairs per XCD = 2
constexpr int GRID_FUSED = NXCD * PAIRS * NCHUNK;  // 1008
constexpr int SL = 80;      // slot stride per node (max in-deg ~52 expected)
constexpr int ECAP = 1536;  // dense staged-edge cap per tile (mean 1024, sd ~32)

constexpr int CVT_BLOCKS  = 8000;  // 8000*256 float4 = 8.192M floats exactly
constexpr int EDGE_BLOCKS = 250;   // 250*256 = 64000 edges exactly

// ---- workspace layout (bytes) ----
constexpr size_t OFF_CNT  = 0;                          // int[2048]    (memset 0)
constexpr size_t OFF_WSUM = OFF_CNT + 2048 * 4;         // float[2048]  (memset 0)
constexpr size_t OFF_SLOT = OFF_WSUM + 2048 * 4;        // int[NN*SL] = 640 KB
constexpr size_t OFF_XBF  = OFF_SLOT + (size_t)NN * SL * 4;  // ushort[NB*NN*ND] = 16.4 MB
constexpr size_t OFF_YP   = OFF_XBF + (size_t)NB * NN * ND * 2;  // float[NB*NCHUNK*ND]
constexpr size_t MEMSET_BYTES = 2048 * 4 * 2;           // cnt + wsum

// f32 -> bf16 (round-to-nearest-even), bit arithmetic; inputs finite
__device__ __forceinline__ ushort f32_to_bf16(float f) {
    uint u = __float_as_uint(f);
    u += 0x7fffu + ((u >> 16) & 1u);
    return (ushort)(u >> 16);
}
} // namespace

// ---- S1: heterogeneous: cvt X->bf16 (blocks 0..7999) + hist/slot (8000..8249) ----
__global__ void k_fill(const float* __restrict__ X, ushort* __restrict__ xbf,
                       const int* __restrict__ src, const int* __restrict__ dst,
                       int* __restrict__ cnt, int* __restrict__ slot) {
    const int blk = blockIdx.x;
    if (blk < CVT_BLOCKS) {
        int i = blk * 256 + threadIdx.x;      // float4 index, exact bounds
        float4 v = ((const float4*)X)[i];
        ushort4 o;
        o.x = f32_to_bf16(v.x);
        o.y = f32_to_bf16(v.y);
        o.z = f32_to_bf16(v.z);
        o.w = f32_to_bf16(v.w);
        ((ushort4*)xbf)[i] = o;
    } else {
        int e = (blk - CVT_BLOCKS) * 256 + threadIdx.x;   // exact bounds
        int s = src[e], d = dst[e];
        int p = atomicAdd(&cnt[d], 1);
        if (p < SL) slot[d * SL + p] = s;     // overflow essentially impossible
    }
}

// ---- S2: wsum out-edge terms (needs final cnt) ----
__global__ void k_wsum(const int* __restrict__ src, const int* __restrict__ dst,
                       const int* __restrict__ cnt, float* __restrict__ wsum) {
    int e = blockIdx.x * 256 + threadIdx.x;
    if (e < NE) {
        int s = src[e], d = dst[e];
        float w = rsqrtf((float)(cnt[s] + 1)) * rsqrtf((float)(cnt[d] + 1));
        atomicAdd(&wsum[s], w);
    }
}

// ---- fused: stage edges once, bf16-gather 2 batches, fp32 GEMM, reduce ----
__global__ __launch_bounds__(256, 3) void k_fused(const ushort* __restrict__ xbf,
                                                  const int* __restrict__ cnt,
                                                  const int* __restrict__ slot,
                                                  const float* __restrict__ wsum,
                                                  const float* __restrict__ W1,
                                                  const float* __restrict__ b1,
                                                  float* __restrict__ ypart) {
    __shared__ float4 As4[2][32 * 33];   // 33792 B, row stride 33 float4
    __shared__ int2   sEdge[ECAP];       // 12288 B (src, w-bits)
    __shared__ int    sCnt[32];
    __shared__ int    sBase[33];
    __shared__ float  sDinv[32];
    __shared__ float  yred[2][128];
    const int tid = threadIdx.x;

    // XCD batch-partition swizzle; block handles batches b0, b0+1 (same graph)
    const int L     = blockIdx.x;
    const int xcd   = L & (NXCD - 1);
    const int sl    = L >> 3;
    const int pair  = sl / NCHUNK;
    const int chunk = sl % NCHUNK;
    const int b0    = xcd * (BPB * PAIRS) + pair * BPB;
    const int n0    = chunk * TR;

    if (tid < 32) {
        int n = n0 + tid;
        int cr = (n < NN) ? cnt[n] : 0;
        sCnt[tid]  = min(cr, SL);
        sDinv[tid] = rsqrtf((float)(cr + 1));
    }
    if (tid < 128) { yred[0][tid] = 0.f; yred[1][tid] = 0.f; }
    __syncthreads();
    if (tid == 0) {
        int s = 0;
        for (int j = 0; j < 32; j++) { sBase[j] = s; s += sCnt[j]; }
        sBase[32] = s;
    }
    __syncthreads();
    const bool staged = (sBase[32] <= ECAP);

    // stage edges: wave wv stages rows wv*8..+7; compute w at staging time
    const int wv = tid >> 6, ln = tid & 63;
    if (staged) {
        for (int ii = 0; ii < 8; ii++) {
            int j = wv * 8 + ii;
            int c = sCnt[j];
            float dd = sDinv[j];
            const int* sp = &slot[(size_t)(n0 + j) * SL];
            for (int base = 0; base < c; base += 64) {
                if (base + ln < c) {
                    int sidx = sp[base + ln];
                    float w = rsqrtf((float)(cnt[sidx] + 1)) * dd;
                    sEdge[sBase[j] + base + ln] = make_int2(sidx, __float_as_int(w));
                }
            }
        }
    }
    __syncthreads();

    // ---- gather: wave owns row; lane ln owns features 2ln,2ln+1 (one u32/row) ----
    // Per edge per batch: ONE dword load (256 B/wave = 4 cache lines).
    const uint* __restrict__ Xu0 = (const uint*)(xbf + (size_t)b0 * NN * ND);
    const uint* __restrict__ Xu1 = (const uint*)(xbf + (size_t)(b0 + 1) * NN * ND);
    float2* A0 = (float2*)As4[0];   // row stride 66 float2
    float2* A1 = (float2*)As4[1];
    #pragma unroll 1
    for (int ii = 0; ii < 8; ii++) {
        const int j = wv * 8 + ii;
        const int n = n0 + j;
        float2 a0 = make_float2(0.f, 0.f), a1 = a0, a0b = a0, a1b = a0;
        if (n < NN) {
            float sn = sDinv[j]; sn *= sn;
            uint u0 = Xu0[n * 64 + ln], u1 = Xu1[n * 64 + ln];
            a0.x = sn * __uint_as_float(u0 << 16);
            a0.y = sn * __uint_as_float(u0 & 0xffff0000u);
            a1.x = sn * __uint_as_float(u1 << 16);
            a1.y = sn * __uint_as_float(u1 & 0xffff0000u);
            const int c = sCnt[j];
            if (staged) {
                const int e0 = sBase[j], e1 = e0 + c;
                int e = e0;
                for (; e + 8 <= e1; e += 8) {
                    int sidx[8]; float w[8]; uint q0[8], q1[8];
                    #pragma unroll
                    for (int q = 0; q < 8; q++) {
                        int2 ed = sEdge[e + q];
                        sidx[q] = ed.x; w[q] = __int_as_float(ed.y);
                    }
                    #pragma unroll
                    for (int q = 0; q < 8; q++) {     // 16 independent 256B loads
                        q0[q] = Xu0[sidx[q] * 64 + ln];
                        q1[q] = Xu1[sidx[q] * 64 + ln];
                    }
                    #pragma unroll
                    for (int q = 0; q < 8; q++) {     // dual accumulators
                        float x0l = __uint_as_float(q0[q] << 16);
                        float x0h = __uint_as_float(q0[q] & 0xffff0000u);
                        float x1l = __uint_as_float(q1[q] << 16);
                        float x1h = __uint_as_float(q1[q] & 0xffff0000u);
                        if (q & 1) {
                            a0b.x = fmaf(w[q], x0l, a0b.x);
                            a0b.y = fmaf(w[q], x0h, a0b.y);
                            a1b.x = fmaf(w[q], x1l, a1b.x);
                            a1b.y = fmaf(w[q], x1h, a1b.y);
                        } else {
                            a0.x = fmaf(w[q], x0l, a0.x);
                            a0.y = fmaf(w[q], x0h, a0.y);
                            a1.x = fmaf(w[q], x1l, a1.x);
                            a1.y = fmaf(w[q], x1h, a1.y);
                        }
                    }
                }
                for (; e < e1; e++) {
                    int2 ed = sEdge[e];
                    float w = __int_as_float(ed.y);
                    uint u0e = Xu0[ed.x * 64 + ln], u1e = Xu1[ed.x * 64 + ln];
                    a0.x = fmaf(w, __uint_as_float(u0e << 16), a0.x);
                    a0.y = fmaf(w, __uint_as_float(u0e & 0xffff0000u), a0.y);
                    a1.x = fmaf(w, __uint_as_float(u1e << 16), a1.x);
                    a1.y = fmaf(w, __uint_as_float(u1e & 0xffff0000u), a1.y);
                }
            } else {
                // astronomically-rare fallback: read slots directly
                const int* sp = &slot[(size_t)n * SL];
                float dd = sDinv[j];
                for (int e = 0; e < c; e++) {
                    int sidx = sp[e];
                    float w = rsqrtf((float)(cnt[sidx] + 1)) * dd;
                    uint u0e = Xu0[sidx * 64 + ln], u1e = Xu1[sidx * 64 + ln];
                    a0.x = fmaf(w, __uint_as_float(u0e << 16), a0.x);
                    a0.y = fmaf(w, __uint_as_float(u0e & 0xffff0000u), a0.y);
                    a1.x = fmaf(w, __uint_as_float(u1e << 16), a1.x);
                    a1.y = fmaf(w, __uint_as_float(u1e & 0xffff0000u), a1.y);
                }
            }
            a0.x += a0b.x; a0.y += a0b.y;
            a1.x += a1b.x; a1.y += a1b.y;
        }
        A0[j * 66 + ln] = a0;
        A1[j * 66 + ln] = a1;
    }
    __syncthreads();

    // ---- GEMM both batches, sharing W loads (fp32) ----
    const int c4 = tid & 31, rg = tid >> 5;
    float4 acc0[4], acc1[4];
    #pragma unroll
    for (int i = 0; i < 4; i++) {
        acc0[i] = make_float4(0.f, 0.f, 0.f, 0.f);
        acc1[i] = make_float4(0.f, 0.f, 0.f, 0.f);
    }
    const float4* __restrict__ W4 = (const float4*)W1 + c4;
    #pragma unroll 2
    for (int k4 = 0; k4 < 32; k4++) {
        float4 w0 = W4[(4 * k4 + 0) * 32];
        float4 w1 = W4[(4 * k4 + 1) * 32];
        float4 w2 = W4[(4 * k4 + 2) * 32];
        float4 w3 = W4[(4 * k4 + 3) * 32];
        #pragma unroll
        for (int i = 0; i < 4; i++) {
            float4 a = As4[0][(rg * 4 + i) * 33 + k4];
            acc0[i].x = fmaf(a.x, w0.x, acc0[i].x); acc0[i].x = fmaf(a.y, w1.x, acc0[i].x);
            acc0[i].x = fmaf(a.z, w2.x, acc0[i].x); acc0[i].x = fmaf(a.w, w3.x, acc0[i].x);
            acc0[i].y = fmaf(a.x, w0.y, acc0[i].y); acc0[i].y = fmaf(a.y, w1.y, acc0[i].y);
            acc0[i].y = fmaf(a.z, w2.y, acc0[i].y); acc0[i].y = fmaf(a.w, w3.y, acc0[i].y);
            acc0[i].z = fmaf(a.x, w0.z, acc0[i].z); acc0[i].z = fmaf(a.y, w1.z, acc0[i].z);
            acc0[i].z = fmaf(a.z, w2.z, acc0[i].z); acc0[i].z = fmaf(a.w, w3.z, acc0[i].z);
            acc0[i].w = fmaf(a.x, w0.w, acc0[i].w); acc0[i].w = fmaf(a.y, w1.w, acc0[i].w);
            acc0[i].w = fmaf(a.z, w2.w, acc0[i].w); acc0[i].w = fmaf(a.w, w3.w, acc0[i].w);
            float4 b = As4[1][(rg * 4 + i) * 33 + k4];
            acc1[i].x = fmaf(b.x, w0.x, acc1[i].x); acc1[i].x = fmaf(b.y, w1.x, acc1[i].x);
            acc1[i].x = fmaf(b.z, w2.x, acc1[i].x); acc1[i].x = fmaf(b.w, w3.x, acc1[i].x);
            acc1[i].y = fmaf(b.x, w0.y, acc1[i].y); acc1[i].y = fmaf(b.y, w1.y, acc1[i].y);
            acc1[i].y = fmaf(b.z, w2.y, acc1[i].y); acc1[i].y = fmaf(b.w, w3.y, acc1[i].y);
            acc1[i].z = fmaf(b.x, w0.z, acc1[i].z); acc1[i].z = fmaf(b.y, w1.z, acc1[i].z);
            acc1[i].z = fmaf(b.z, w2.z, acc1[i].z); acc1[i].z = fmaf(b.w, w3.z, acc1[i].z);
            acc1[i].w = fmaf(b.x, w0.w, acc1[i].w); acc1[i].w = fmaf(b.y, w1.w, acc1[i].w);
            acc1[i].w = fmaf(b.z, w2.w, acc1[i].w); acc1[i].w = fmaf(b.w, w3.w, acc1[i].w);
        }
    }

    // ---- epilogue: relu + weighted reduce, both batches ----
    float wn[4];
    #pragma unroll
    for (int i = 0; i < 4; i++) {
        int j = rg * 4 + i, n = n0 + j;
        float sd = sDinv[j];
        wn[i] = (n < NN) ? (wsum[n] + sd * sd) : 0.f;
    }
    float4 bias = ((const float4*)b1)[c4];
    float4 ya0 = make_float4(0.f, 0.f, 0.f, 0.f);
    float4 ya1 = ya0;
    #pragma unroll
    for (int i = 0; i < 4; i++) {
        ya0.x = fmaf(wn[i], fmaxf(acc0[i].x + bias.x, 0.f), ya0.x);
        ya0.y = fmaf(wn[i], fmaxf(acc0[i].y + bias.y, 0.f), ya0.y);
        ya0.z = fmaf(wn[i], fmaxf(acc0[i].z + bias.z, 0.f), ya0.z);
        ya0.w = fmaf(wn[i], fmaxf(acc0[i].w + bias.w, 0.f), ya0.w);
        ya1.x = fmaf(wn[i], fmaxf(acc1[i].x + bias.x, 0.f), ya1.x);
        ya1.y = fmaf(wn[i], fmaxf(acc1[i].y + bias.y, 0.f), ya1.y);
        ya1.z = fmaf(wn[i], fmaxf(acc1[i].z + bias.z, 0.f), ya1.z);
        ya1.w = fmaf(wn[i], fmaxf(acc1[i].w + bias.w, 0.f), ya1.w);
    }
    atomicAdd(&yred[0][4 * c4 + 0], ya0.x); atomicAdd(&yred[0][4 * c4 + 1], ya0.y);
    atomicAdd(&yred[0][4 * c4 + 2], ya0.z); atomicAdd(&yred[0][4 * c4 + 3], ya0.w);
    atomicAdd(&yred[1][4 * c4 + 0], ya1.x); atomicAdd(&yred[1][4 * c4 + 1], ya1.y);
    atomicAdd(&yred[1][4 * c4 + 2], ya1.z); atomicAdd(&yred[1][4 * c4 + 3], ya1.w);
    __syncthreads();
    if (tid < 128)
        ypart[((size_t)b0 * NCHUNK + chunk) * ND + tid] = yred[0][tid];
    else
        ypart[((size_t)(b0 + 1) * NCHUNK + chunk) * ND + (tid - 128)] = yred[1][tid - 128];
}

// ---- out[b,:] = (1/N) * (sum_chunk ypart[b,chunk,:]) @ W2 + b2 ----
__global__ __launch_bounds__(128) void k_out(const float* __restrict__ ypart,
                                             const float* __restrict__ W2,
                                             const float* __restrict__ b2,
                                             float* __restrict__ out) {
    __shared__ float ys[128];
    const int b = blockIdx.x;
    const int d = threadIdx.x;
    float s = 0.f;
    for (int c = 0; c < NCHUNK; c++)
        s += ypart[((size_t)b * NCHUNK + c) * ND + d];
    ys[d] = s * (1.f / (float)NN);
    __syncthreads();
    float acc = b2[d];
    #pragma unroll 8
    for (int k = 0; k < 128; k++)
        acc = fmaf(ys[k], W2[k * ND + d], acc);
    out[b * ND + d] = acc;
}

extern "C" void kernel_launch(void* const* d_in, const int* in_sizes, int n_in,
                              void* d_out, int out_size, void* d_ws, size_t ws_size,
                              hipStream_t stream) {
    (void)in_sizes; (void)n_in; (void)out_size; (void)ws_size;
    const float* X   = (const float*)d_in[0];
    const int*   src = (const int*)d_in[1];
    const int*   dst = (const int*)d_in[2];
    const float* W1  = (const float*)d_in[3];
    const float* b1  = (const float*)d_in[4];
    const float* W2  = (const float*)d_in[5];
    const float* b2  = (const float*)d_in[6];
    float* out = (float*)d_out;

    char* ws = (char*)d_ws;
    int*    cnt   = (int*)   (ws + OFF_CNT);
    float*  wsum  = (float*) (ws + OFF_WSUM);
    int*    slot  = (int*)   (ws + OFF_SLOT);
    ushort* xbf   = (ushort*)(ws + OFF_XBF);
    float*  ypart = (float*) (ws + OFF_YP);

    (void)hipMemsetAsync(ws, 0, MEMSET_BYTES, stream);            // cnt + wsum
    k_fill<<<CVT_BLOCKS + EDGE_BLOCKS, 256, 0, stream>>>(X, xbf, src, dst, cnt, slot);
    k_wsum<<<EDGE_BLOCKS, 256, 0, stream>>>(src, dst, cnt, wsum);
    k_fused<<<GRID_FUSED, 256, 0, stream>>>(xbf, cnt, slot, wsum, W1, b1, ypart);
    k_out<<<NB, 128, 0, stream>>>(ypart, W2, b2, out);
}

// Round 10
// 164.589 us; speedup vs baseline: 1.3156x; 1.1898x over previous
//
#include <hip/hip_runtime.h>

namespace {
constexpr int NB = 32;      // batch
constexpr int NN = 2000;    // nodes
constexpr int NE = 64000;   // edges
constexpr int ND = 128;     // feature dim
constexpr int TR = 32;      // tile rows
constexpr int NCHUNK = (NN + TR - 1) / TR;   // 63
constexpr int NXCD = 8;
constexpr int BPB = 2;                        // batches per block
constexpr int PAIRS = NB / (NXCD * BPB);      // batch-pairs per XCD = 2
constexpr int GRID_FUSED = NXCD * PAIRS * NCHUNK;  // 1008
constexpr int SL = 80;      // slot stride per node (max in-deg ~52 expected)
constexpr int ECAP = 1536;  // dense staged-edge cap per tile (mean 1024, sd ~32)

constexpr int CVT_BLOCKS  = 8000;  // 8000*256 float4 = 8.192M floats exactly
constexpr int W_BLOCKS    = 8;     // 2048 threads: one per (frag,lane) of W1 prepack
constexpr int EDGE_BLOCKS = 250;   // 250*256 = 64000 edges exactly

// ---- workspace layout (bytes) ----
constexpr size_t OFF_CNT  = 0;                          // int[2048]    (memset 0)
constexpr size_t OFF_WSUM = OFF_CNT + 2048 * 4;         // float[2048]  (memset 0)
constexpr size_t OFF_SLOT = OFF_WSUM + 2048 * 4;        // int[NN*SL] = 640 KB
constexpr size_t OFF_WF   = OFF_SLOT + (size_t)NN * SL * 4;   // bf16 W1 frags, 32 KB
constexpr size_t OFF_XBF  = OFF_WF + 32768;             // ushort[NB*NN*ND] = 16.4 MB
constexpr size_t OFF_YP   = OFF_XBF + (size_t)NB * NN * ND * 2;  // float[NB*NCHUNK*ND]
constexpr size_t MEMSET_BYTES = 2048 * 4 * 2;           // cnt + wsum

typedef __attribute__((ext_vector_type(8))) short bf16x8;
typedef __attribute__((ext_vector_type(4))) float f32x4;

// f32 -> bf16 (round-to-nearest-even), bit arithmetic; inputs finite
__device__ __forceinline__ ushort f32_to_bf16(float f) {
    uint u = __float_as_uint(f);
    u += 0x7fffu + ((u >> 16) & 1u);
    return (ushort)(u >> 16);
}
__device__ __forceinline__ uint pack_bf16x2(float lo, float hi) {
    return (uint)f32_to_bf16(lo) | ((uint)f32_to_bf16(hi) << 16);
}
} // namespace

// ---- S1: heterogeneous: cvt X->bf16 | W1 frag prepack | hist/slot ----
__global__ void k_fill(const float* __restrict__ X, ushort* __restrict__ xbf,
                       const float* __restrict__ W1, uint* __restrict__ wf,
                       const int* __restrict__ src, const int* __restrict__ dst,
                       int* __restrict__ cnt, int* __restrict__ slot) {
    const int blk = blockIdx.x;
    if (blk < CVT_BLOCKS) {
        int i = blk * 256 + threadIdx.x;      // float4 index, exact bounds
        float4 v = ((const float4*)X)[i];
        ushort4 o;
        o.x = f32_to_bf16(v.x);
        o.y = f32_to_bf16(v.y);
        o.z = f32_to_bf16(v.z);
        o.w = f32_to_bf16(v.w);
        ((ushort4*)xbf)[i] = o;
    } else if (blk < CVT_BLOCKS + W_BLOCKS) {
        // W1 -> MFMA B-fragment layout (16x16x32 bf16):
        // frag f = nt*4+kc; lane l holds W1[k = kc*32 + (l>>4)*8 + j][nt*16 + (l&15)]
        int g = (blk - CVT_BLOCKS) * 256 + threadIdx.x;   // 0..2047
        int lane = g & 63, f = g >> 6;                    // f 0..31
        int nt = f >> 2, kc = f & 3;
        int col = nt * 16 + (lane & 15);
        int k0  = kc * 32 + (lane >> 4) * 8;
        uint4 o;
        o.x = pack_bf16x2(W1[(k0 + 0) * ND + col], W1[(k0 + 1) * ND + col]);
        o.y = pack_bf16x2(W1[(k0 + 2) * ND + col], W1[(k0 + 3) * ND + col]);
        o.z = pack_bf16x2(W1[(k0 + 4) * ND + col], W1[(k0 + 5) * ND + col]);
        o.w = pack_bf16x2(W1[(k0 + 6) * ND + col], W1[(k0 + 7) * ND + col]);
        ((uint4*)wf)[g] = o;
    } else {
        int e = (blk - CVT_BLOCKS - W_BLOCKS) * 256 + threadIdx.x;   // exact bounds
        int s = src[e], d = dst[e];
        int p = atomicAdd(&cnt[d], 1);
        if (p < SL) slot[d * SL + p] = s;     // overflow essentially impossible
    }
}

// ---- S2: wsum out-edge terms (needs final cnt) ----
__global__ void k_wsum(const int* __restrict__ src, const int* __restrict__ dst,
                       const int* __restrict__ cnt, float* __restrict__ wsum) {
    int e = blockIdx.x * 256 + threadIdx.x;
    if (e < NE) {
        int s = src[e], d = dst[e];
        float w = rsqrtf((float)(cnt[s] + 1)) * rsqrtf((float)(cnt[d] + 1));
        atomicAdd(&wsum[s], w);
    }
}

// ---- fused: stage edges, bf16-gather 2 batches, MFMA GEMM, weighted reduce ----
__global__ __launch_bounds__(256, 4) void k_fused(const ushort* __restrict__ xbf,
                                                  const int* __restrict__ cnt,
                                                  const int* __restrict__ slot,
                                                  const float* __restrict__ wsum,
                                                  const uint* __restrict__ wfrag,
                                                  const float* __restrict__ b1,
                                                  float* __restrict__ ypart) {
    __shared__ uint  AsU[2][32 * 68];   // bf16 A, row stride 136 bf16 (68 uints); 17408 B
    __shared__ int2  sEdge[ECAP];       // 12288 B (src, w-bits)
    __shared__ int   sCnt[32];
    __shared__ int   sBase[33];
    __shared__ float sDinv[32];
    __shared__ float sWn[32];
    __shared__ float yred[2][128];
    const int tid = threadIdx.x;

    // XCD batch-partition swizzle; block handles batches b0, b0+1 (same graph)
    const int L     = blockIdx.x;
    const int xcd   = L & (NXCD - 1);
    const int sl    = L >> 3;
    const int pair  = sl / NCHUNK;
    const int chunk = sl % NCHUNK;
    const int b0    = xcd * (BPB * PAIRS) + pair * BPB;
    const int n0    = chunk * TR;

    if (tid < 32) {
        int n = n0 + tid;
        int cr = (n < NN) ? cnt[n] : 0;
        float d = rsqrtf((float)(cr + 1));
        sCnt[tid]  = min(cr, SL);
        sDinv[tid] = d;
        sWn[tid]   = (n < NN) ? (wsum[n] + d * d) : 0.f;
    }
    if (tid < 128) { yred[0][tid] = 0.f; yred[1][tid] = 0.f; }
    __syncthreads();
    if (tid == 0) {
        int s = 0;
        for (int j = 0; j < 32; j++) { sBase[j] = s; s += sCnt[j]; }
        sBase[32] = s;
    }
    __syncthreads();
    const bool staged = (sBase[32] <= ECAP);

    // stage edges: wave wv stages rows wv*8..+7; compute w at staging time
    const int wv = tid >> 6, ln = tid & 63;
    if (staged) {
        for (int ii = 0; ii < 8; ii++) {
            int j = wv * 8 + ii;
            int c = sCnt[j];
            float dd = sDinv[j];
            const int* sp = &slot[(size_t)(n0 + j) * SL];
            for (int base = 0; base < c; base += 64) {
                if (base + ln < c) {
                    int sidx = sp[base + ln];
                    float w = rsqrtf((float)(cnt[sidx] + 1)) * dd;
                    sEdge[sBase[j] + base + ln] = make_int2(sidx, __float_as_int(w));
                }
            }
        }
    }
    __syncthreads();

    // ---- gather: wave owns row; lane ln owns features 2ln,2ln+1 (one u32/row) ----
    const uint* __restrict__ Xu0 = (const uint*)(xbf + (size_t)b0 * NN * ND);
    const uint* __restrict__ Xu1 = (const uint*)(xbf + (size_t)(b0 + 1) * NN * ND);
    #pragma unroll 1
    for (int ii = 0; ii < 8; ii++) {
        const int j = wv * 8 + ii;
        const int n = n0 + j;
        float2 a0 = make_float2(0.f, 0.f), a1 = a0, a0b = a0, a1b = a0;
        if (n < NN) {
            float sn = sDinv[j]; sn *= sn;
            uint u0 = Xu0[n * 64 + ln], u1 = Xu1[n * 64 + ln];
            a0.x = sn * __uint_as_float(u0 << 16);
            a0.y = sn * __uint_as_float(u0 & 0xffff0000u);
            a1.x = sn * __uint_as_float(u1 << 16);
            a1.y = sn * __uint_as_float(u1 & 0xffff0000u);
            const int c = sCnt[j];
            if (staged) {
                const int e0 = sBase[j], e1 = e0 + c;
                int e = e0;
                for (; e + 8 <= e1; e += 8) {
                    int sidx[8]; float w[8]; uint q0[8], q1[8];
                    #pragma unroll
                    for (int q = 0; q < 8; q++) {
                        int2 ed = sEdge[e + q];
                        sidx[q] = ed.x; w[q] = __int_as_float(ed.y);
                    }
                    #pragma unroll
                    for (int q = 0; q < 8; q++) {     // 16 independent 256B loads
                        q0[q] = Xu0[sidx[q] * 64 + ln];
                        q1[q] = Xu1[sidx[q] * 64 + ln];
                    }
                    #pragma unroll
                    for (int q = 0; q < 8; q++) {     // dual accumulators
                        float x0l = __uint_as_float(q0[q] << 16);
                        float x0h = __uint_as_float(q0[q] & 0xffff0000u);
                        float x1l = __uint_as_float(q1[q] << 16);
                        float x1h = __uint_as_float(q1[q] & 0xffff0000u);
                        if (q & 1) {
                            a0b.x = fmaf(w[q], x0l, a0b.x);
                            a0b.y = fmaf(w[q], x0h, a0b.y);
                            a1b.x = fmaf(w[q], x1l, a1b.x);
                            a1b.y = fmaf(w[q], x1h, a1b.y);
                        } else {
                            a0.x = fmaf(w[q], x0l, a0.x);
                            a0.y = fmaf(w[q], x0h, a0.y);
                            a1.x = fmaf(w[q], x1l, a1.x);
                            a1.y = fmaf(w[q], x1h, a1.y);
                        }
                    }
                }
                for (; e < e1; e++) {
                    int2 ed = sEdge[e];
                    float w = __int_as_float(ed.y);
                    uint u0e = Xu0[ed.x * 64 + ln], u1e = Xu1[ed.x * 64 + ln];
                    a0.x = fmaf(w, __uint_as_float(u0e << 16), a0.x);
                    a0.y = fmaf(w, __uint_as_float(u0e & 0xffff0000u), a0.y);
                    a1.x = fmaf(w, __uint_as_float(u1e << 16), a1.x);
                    a1.y = fmaf(w, __uint_as_float(u1e & 0xffff0000u), a1.y);
                }
            } else {
                // astronomically-rare fallback: read slots directly
                const int* sp = &slot[(size_t)n * SL];
                float dd = sDinv[j];
                for (int e = 0; e < c; e++) {
                    int sidx = sp[e];
                    float w = rsqrtf((float)(cnt[sidx] + 1)) * dd;
                    uint u0e = Xu0[sidx * 64 + ln], u1e = Xu1[sidx * 64 + ln];
                    a0.x = fmaf(w, __uint_as_float(u0e << 16), a0.x);
                    a0.y = fmaf(w, __uint_as_float(u0e & 0xffff0000u), a0.y);
                    a1.x = fmaf(w, __uint_as_float(u1e << 16), a1.x);
                    a1.y = fmaf(w, __uint_as_float(u1e & 0xffff0000u), a1.y);
                }
            }
            a0.x += a0b.x; a0.y += a0b.y;
            a1.x += a1b.x; a1.y += a1b.y;
        }
        AsU[0][j * 68 + ln] = pack_bf16x2(a0.x, a0.y);   // features 2ln, 2ln+1
        AsU[1][j * 68 + ln] = pack_bf16x2(a1.x, a1.y);
    }
    __syncthreads();

    // ---- MFMA GEMM: wave wv owns n-tiles {2wv, 2wv+1}; 32 mfma per wave ----
    // A-frag: lane l = A[m = mt*16 + (l&15)][k = kc*32 + (l>>4)*8 + j]
    // B-frag (prepacked): lane l = W1[k = kc*32 + (l>>4)*8 + j][n = nt*16 + (l&15)]
    // C/D: col = l&15 (N), row = (l>>4)*4 + reg (M)
    const int lane15 = ln & 15, quad = ln >> 4;
    f32x4 zero4 = {0.f, 0.f, 0.f, 0.f};
    f32x4 acc[2][2][2];                  // [batch][mt][nt2]
    #pragma unroll
    for (int b = 0; b < 2; b++)
        #pragma unroll
        for (int mt = 0; mt < 2; mt++)
            #pragma unroll
            for (int nt2 = 0; nt2 < 2; nt2++) acc[b][mt][nt2] = zero4;

    bf16x8 wf[2][4];
    const bf16x8* Wf8 = (const bf16x8*)wfrag;
    #pragma unroll
    for (int nt2 = 0; nt2 < 2; nt2++)
        #pragma unroll
        for (int kc = 0; kc < 4; kc++)
            wf[nt2][kc] = Wf8[(((2 * wv + nt2) * 4 + kc) * 64) + ln];

    const bf16x8* A8_0 = (const bf16x8*)AsU[0];   // row stride 17 frags (136 bf16)
    const bf16x8* A8_1 = (const bf16x8*)AsU[1];
    #pragma unroll
    for (int mt = 0; mt < 2; mt++) {
        const int r = mt * 16 + lane15;
        #pragma unroll
        for (int kc = 0; kc < 4; kc++) {
            bf16x8 af0 = A8_0[r * 17 + kc * 4 + quad];
            bf16x8 af1 = A8_1[r * 17 + kc * 4 + quad];
            #pragma unroll
            for (int nt2 = 0; nt2 < 2; nt2++) {
                acc[0][mt][nt2] = __builtin_amdgcn_mfma_f32_16x16x32_bf16(
                    af0, wf[nt2][kc], acc[0][mt][nt2], 0, 0, 0);
                acc[1][mt][nt2] = __builtin_amdgcn_mfma_f32_16x16x32_bf16(
                    af1, wf[nt2][kc], acc[1][mt][nt2], 0, 0, 0);
            }
        }
    }

    // ---- epilogue: relu + wsum-weighted reduce (C-layout aware) ----
    #pragma unroll
    for (int nt2 = 0; nt2 < 2; nt2++) {
        int cg = (2 * wv + nt2) * 16 + lane15;
        float bias = b1[cg];
        #pragma unroll
        for (int b = 0; b < 2; b++) {
            float part = 0.f;
            #pragma unroll
            for (int mt = 0; mt < 2; mt++) {
                f32x4 a = acc[b][mt][nt2];
                #pragma unroll
                for (int r = 0; r < 4; r++) {
                    int m = mt * 16 + quad * 4 + r;
                    part = fmaf(sWn[m], fmaxf(a[r] + bias, 0.f), part);
                }
            }
            atomicAdd(&yred[b][cg], part);
        }
    }
    __syncthreads();
    if (tid < 128)
        ypart[((size_t)b0 * NCHUNK + chunk) * ND + tid] = yred[0][tid];
    else
        ypart[((size_t)(b0 + 1) * NCHUNK + chunk) * ND + (tid - 128)] = yred[1][tid - 128];
}

// ---- out[b,:] = (1/N) * (sum_chunk ypart[b,chunk,:]) @ W2 + b2 ----
__global__ __launch_bounds__(128) void k_out(const float* __restrict__ ypart,
                                             const float* __restrict__ W2,
                                             const float* __restrict__ b2,
                                             float* __restrict__ out) {
    __shared__ float ys[128];
    const int b = blockIdx.x;
    const int d = threadIdx.x;
    float s = 0.f;
    for (int c = 0; c < NCHUNK; c++)
        s += ypart[((size_t)b * NCHUNK + c) * ND + d];
    ys[d] = s * (1.f / (float)NN);
    __syncthreads();
    float acc = b2[d];
    #pragma unroll 8
    for (int k = 0; k < 128; k++)
        acc = fmaf(ys[k], W2[k * ND + d], acc);
    out[b * ND + d] = acc;
}

extern "C" void kernel_launch(void* const* d_in, const int* in_sizes, int n_in,
                              void* d_out, int out_size, void* d_ws, size_t ws_size,
                              hipStream_t stream) {
    (void)in_sizes; (void)n_in; (void)out_size; (void)ws_size;
    const float* X   = (const float*)d_in[0];
    const int*   src = (const int*)d_in[1];
    const int*   dst = (const int*)d_in[2];
    const float* W1  = (const float*)d_in[3];
    const float* b1  = (const float*)d_in[4];
    const float* W2  = (const float*)d_in[5];
    const float* b2  = (const float*)d_in[6];
    float* out = (float*)d_out;

    char* ws = (char*)d_ws;
    int*    cnt   = (int*)   (ws + OFF_CNT);
    float*  wsum  = (float*) (ws + OFF_WSUM);
    int*    slot  = (int*)   (ws + OFF_SLOT);
    uint*   wfb   = (uint*)  (ws + OFF_WF);
    ushort* xbf   = (ushort*)(ws + OFF_XBF);
    float*  ypart = (float*) (ws + OFF_YP);

    (void)hipMemsetAsync(ws, 0, MEMSET_BYTES, stream);            // cnt + wsum
    k_fill<<<CVT_BLOCKS + W_BLOCKS + EDGE_BLOCKS, 256, 0, stream>>>(
        X, xbf, W1, wfb, src, dst, cnt, slot);
    k_wsum<<<EDGE_BLOCKS, 256, 0, stream>>>(src, dst, cnt, wsum);
    k_fused<<<GRID_FUSED, 256, 0, stream>>>(xbf, cnt, slot, wsum, wfb, b1, ypart);
    k_out<<<NB, 128, 0, stream>>>(ypart, W2, b2, out);
}